// Round 3
// baseline (360.274 us; speedup 1.0000x reference)
//
#include <hip/hip_runtime.h>
#include <hip/hip_bf16.h>

#define B_  2
#define S_  2048
#define H_  24
#define DH_ 32
#define E_  768
#define SW_ (S_/32)   // mask words per row = 64

typedef __attribute__((ext_vector_type(8))) short short8;   // 8 x bf16 bits
typedef __attribute__((ext_vector_type(4))) float f32x4;

static __device__ __forceinline__ short bf16bits(float f) {
    __hip_bfloat16 h = __float2bfloat16(f);
    return *reinterpret_cast<short*>(&h);
}

// exp(-1e-6f) — the "masked" probability under the reference's quirk
#define MEXP 0.99999899864f

// ---------------------------------------------------------------------------
// Kernel 0a: pack int32 mask -> bitmask via wave ballot.
// Each wave reads 64 contiguous ints (coalesced), lane 0 stores 8B of bits.
// ---------------------------------------------------------------------------
__global__ __launch_bounds__(256) void maskpack_kernel(
    const int* __restrict__ mask, unsigned int* __restrict__ mbits)
{
    const int idx  = blockIdx.x * 256 + threadIdx.x;
    const int lane = threadIdx.x & 63;
    const unsigned long long bal = __ballot(mask[idx] != 0);
    if (lane == 0) {
        uint2 w;
        w.x = (unsigned int)(bal & 0xffffffffull);
        w.y = (unsigned int)(bal >> 32);
        *reinterpret_cast<uint2*>(mbits + (idx >> 5)) = w;   // idx is 64-aligned here
    }
}

// ---------------------------------------------------------------------------
// Kernel 0b: Wo fp32 -> bf16 (one-time; removes cvt VALU from proj K-loop)
// ---------------------------------------------------------------------------
__global__ __launch_bounds__(256) void woconv_kernel(
    const float* __restrict__ Wo, __hip_bfloat16* __restrict__ Wob)
{
    const int i = (blockIdx.x * 256 + threadIdx.x) * 4;
    const float4 w = *reinterpret_cast<const float4*>(Wo + i);
    short4 o;
    o.x = bf16bits(w.x); o.y = bf16bits(w.y);
    o.z = bf16bits(w.z); o.w = bf16bits(w.w);
    *reinterpret_cast<short4*>(Wob + i) = o;
}

// ---------------------------------------------------------------------------
// Kernel 1: per-head QKV projection, 64 s-rows per block (8x weight amortize).
// Q written PRE-SCALED by 1/sqrt(DH). V stored transposed [d][s].
// grid = (S/64, B*H), block = 256 (8 s-rows x 32 e-cols per pass, 8 passes)
// ---------------------------------------------------------------------------
__global__ __launch_bounds__(256) void qkv_kernel(
    const float* __restrict__ x,
    const float* __restrict__ Wq,
    const float* __restrict__ Wk,
    const float* __restrict__ Wv,
    __hip_bfloat16* __restrict__ Qo,
    __hip_bfloat16* __restrict__ Ko,
    __hip_bfloat16* __restrict__ Vto)
{
    const int bh = blockIdx.y;
    const int b  = bh / H_;
    const int h  = bh - b * H_;
    const int t  = threadIdx.x;
    const int e  = t & 31;
    const int sl = t >> 5;
    const int s0 = blockIdx.x * 64;

    __shared__ float xs[64][32];
    __shared__ float wqT[32][33];   // [e][d], +1 pad
    __shared__ float wkT[32][33];
    __shared__ float wvT[32][33];

    const size_t wbase = (size_t)h * DH_ * DH_;
    for (int i = t; i < DH_ * DH_; i += 256) {
        const int d = i >> 5, ee = i & 31;
        wqT[ee][d] = Wq[wbase + i];
        wkT[ee][d] = Wk[wbase + i];
        wvT[ee][d] = Wv[wbase + i];
    }
#pragma unroll
    for (int rr = 0; rr < 8; ++rr) {
        const int sr = rr * 8 + sl;
        xs[sr][e] = x[((size_t)b * S_ + s0 + sr) * E_ + h * DH_ + e];
    }
    __syncthreads();

    const float scale = 0.17677669529663687f;   // 1/sqrt(32)
#pragma unroll
    for (int rr = 0; rr < 8; ++rr) {
        const int sr = rr * 8 + sl;
        const int s  = s0 + sr;
        float q = 0.f, k = 0.f, v = 0.f;
#pragma unroll
        for (int d = 0; d < DH_; ++d) {
            const float xv = xs[sr][d];
            q += xv * wqT[e][d];
            k += xv * wkT[e][d];
            v += xv * wvT[e][d];
        }
        const size_t rowq = ((size_t)bh * S_ + s) * DH_ + e;
        Qo[rowq] = __float2bfloat16(q * scale);      // pre-scaled
        Ko[rowq] = __float2bfloat16(k);
        Vto[((size_t)bh * DH_ + e) * S_ + s] = __float2bfloat16(v);
    }
}

// ---------------------------------------------------------------------------
// Kernel 2: fused attention v2.
//  - 64 keys/iteration as two independent 32-key chunk pipelines (A,B) with
//    separate O accumulators -> 2x ILP, half the iterations.
//  - bit-packed mask: one uint2 broadcast load per q-row per iteration.
//  - K rows loaded interleaved (lane col -> keys 2col,2col+1) so each lane's
//    two P values are ADJACENT keys -> packed bf16x2 b32 LDS writes.
//  - Q pre-scaled; masked prob is the constant exp(-1e-6).
// MFMA 16x16x32 bf16; C/D: col=lane&15, row=quad*4+reg (m89);
// A/B operand: elem[n=lane&15][k=quad*8+j] (m120).
// grid = (S/64, B*H), block = 256 (4 waves x 16 q-rows)
// ---------------------------------------------------------------------------
__global__ __launch_bounds__(256) void attn_kernel(
    const __hip_bfloat16* __restrict__ Q,     // [B*H][S][DH] (pre-scaled)
    const __hip_bfloat16* __restrict__ K,     // [B*H][S][DH]
    const __hip_bfloat16* __restrict__ Vt,    // [B*H][DH][S]
    const unsigned int* __restrict__ mbits,   // [B][S][S/32]
    __hip_bfloat16* __restrict__ attnout)     // [B][S][E]
{
    const int bh   = blockIdx.y;
    const int b    = bh / H_;
    const int h    = bh - b * H_;
    const int wave = threadIdx.x >> 6;
    const int lane = threadIdx.x & 63;
    const int col  = lane & 15;
    const int quad = lane >> 4;
    const int q0   = blockIdx.x * 64 + wave * 16;

    const __hip_bfloat16* Qbh = Q  + (size_t)bh * S_ * DH_;
    const __hip_bfloat16* Kbh = K  + (size_t)bh * S_ * DH_;
    const __hip_bfloat16* Vbh = Vt + (size_t)bh * DH_ * S_;
    const unsigned int*   mbb = mbits + (size_t)b * S_ * SW_;

    const short8 qfrag =
        *reinterpret_cast<const short8*>(Qbh + (size_t)(q0 + col) * DH_ + quad * 8);

    f32x4 oA0 = {0.f,0.f,0.f,0.f}, oA1 = {0.f,0.f,0.f,0.f};
    f32x4 oB0 = {0.f,0.f,0.f,0.f}, oB1 = {0.f,0.f,0.f,0.f};
    float lacc[4] = {0.f, 0.f, 0.f, 0.f};

    // per-wave P repack buffers, row stride 40 bf16 (80B): b32 writes 2-way
    // bank aliasing at worst (free, m136); b128 reads 16B-aligned.
    __shared__ __align__(16) __hip_bfloat16 pbufA[4][16][40];
    __shared__ __align__(16) __hip_bfloat16 pbufB[4][16][40];

    for (int k0 = 0; k0 < S_; k0 += 64) {
        // --- K fragments, interleaved: lane col covers keys k0+2col, +1 ---
        const size_t rA = (size_t)(k0 + 2 * col) * DH_ + quad * 8;
        const size_t rB = (size_t)(k0 + 32 + 2 * col) * DH_ + quad * 8;
        const short8 kA0 = *reinterpret_cast<const short8*>(Kbh + rA);
        const short8 kA1 = *reinterpret_cast<const short8*>(Kbh + rA + DH_);
        const short8 kB0 = *reinterpret_cast<const short8*>(Kbh + rB);
        const short8 kB1 = *reinterpret_cast<const short8*>(Kbh + rB + DH_);

        const f32x4 z = {0.f, 0.f, 0.f, 0.f};
        f32x4 sA0 = __builtin_amdgcn_mfma_f32_16x16x32_bf16(qfrag, kA0, z, 0, 0, 0);
        f32x4 sA1 = __builtin_amdgcn_mfma_f32_16x16x32_bf16(qfrag, kA1, z, 0, 0, 0);
        f32x4 sB0 = __builtin_amdgcn_mfma_f32_16x16x32_bf16(qfrag, kB0, z, 0, 0, 0);
        f32x4 sB1 = __builtin_amdgcn_mfma_f32_16x16x32_bf16(qfrag, kB1, z, 0, 0, 0);

#pragma unroll
        for (int r = 0; r < 4; ++r) {
            const int row  = quad * 4 + r;
            const int qrow = q0 + row;
            const uint2 mw = *reinterpret_cast<const uint2*>(
                mbb + (size_t)qrow * SW_ + (k0 >> 5));
            const unsigned bA = (mw.x >> (2 * col)) & 3u;
            const unsigned bB = (mw.y >> (2 * col)) & 3u;
            const float pA0 = (bA & 1u) ? __expf(sA0[r]) : MEXP;
            const float pA1 = (bA & 2u) ? __expf(sA1[r]) : MEXP;
            const float pB0 = (bB & 1u) ? __expf(sB0[r]) : MEXP;
            const float pB1 = (bB & 2u) ? __expf(sB1[r]) : MEXP;
            lacc[r] += (pA0 + pA1) + (pB0 + pB1);
            float2 fA; fA.x = pA0; fA.y = pA1;
            float2 fB; fB.x = pB0; fB.y = pB1;
            *reinterpret_cast<__hip_bfloat162*>(&pbufA[wave][row][2 * col]) =
                __float22bfloat162_rn(fA);
            *reinterpret_cast<__hip_bfloat162*>(&pbufB[wave][row][2 * col]) =
                __float22bfloat162_rn(fB);
        }

        // C-layout -> A-layout (per-wave LDS round-trip; in-wave DS is ordered)
        const short8 pfA = *reinterpret_cast<const short8*>(&pbufA[wave][col][quad * 8]);
        const short8 pfB = *reinterpret_cast<const short8*>(&pbufB[wave][col][quad * 8]);

        const short8 vA0 = *reinterpret_cast<const short8*>(
            Vbh + (size_t)col * S_ + k0 + quad * 8);
        const short8 vA1 = *reinterpret_cast<const short8*>(
            Vbh + (size_t)(16 + col) * S_ + k0 + quad * 8);
        const short8 vB0 = *reinterpret_cast<const short8*>(
            Vbh + (size_t)col * S_ + k0 + 32 + quad * 8);
        const short8 vB1 = *reinterpret_cast<const short8*>(
            Vbh + (size_t)(16 + col) * S_ + k0 + 32 + quad * 8);

        oA0 = __builtin_amdgcn_mfma_f32_16x16x32_bf16(pfA, vA0, oA0, 0, 0, 0);
        oA1 = __builtin_amdgcn_mfma_f32_16x16x32_bf16(pfA, vA1, oA1, 0, 0, 0);
        oB0 = __builtin_amdgcn_mfma_f32_16x16x32_bf16(pfB, vB0, oB0, 0, 0, 0);
        oB1 = __builtin_amdgcn_mfma_f32_16x16x32_bf16(pfB, vB1, oB1, 0, 0, 0);
    }

#pragma unroll
    for (int r = 0; r < 4; ++r) {
        float l = lacc[r];
        l += __shfl_xor(l, 1);
        l += __shfl_xor(l, 2);
        l += __shfl_xor(l, 4);
        l += __shfl_xor(l, 8);
        const float linv = 1.0f / l;
        const int qrow = q0 + quad * 4 + r;
        __hip_bfloat16* orow = attnout + ((size_t)b * S_ + qrow) * E_ + h * DH_;
        orow[col]      = __float2bfloat16((oA0[r] + oB0[r]) * linv);
        orow[16 + col] = __float2bfloat16((oA1[r] + oB1[r]) * linv);
    }
}

// ---------------------------------------------------------------------------
// Kernel 3: output projection with pre-converted bf16 Wo.
// Each wave: 32 m-rows x 64 n-cols (2x A-frag reuse of each B-frag).
// grid = (M/32, 768/256), block = 256.
// ---------------------------------------------------------------------------
__global__ __launch_bounds__(256) void proj_kernel(
    const __hip_bfloat16* __restrict__ A,     // [4096][768] bf16 (ws)
    const __hip_bfloat16* __restrict__ Wob,   // [768][768] bf16 (ws)
    const float* __restrict__ bo,             // [768] fp32
    float* __restrict__ out)                  // [4096][768] fp32
{
    const int wave = threadIdx.x >> 6;
    const int lane = threadIdx.x & 63;
    const int col  = lane & 15;
    const int quad = lane >> 4;
    const int m0   = blockIdx.x * 32;
    const int n0   = blockIdx.y * 256 + wave * 64;

    f32x4 acc[2][4] = {{{0.f,0.f,0.f,0.f},{0.f,0.f,0.f,0.f},
                        {0.f,0.f,0.f,0.f},{0.f,0.f,0.f,0.f}},
                       {{0.f,0.f,0.f,0.f},{0.f,0.f,0.f,0.f},
                        {0.f,0.f,0.f,0.f},{0.f,0.f,0.f,0.f}}};
    for (int k0 = 0; k0 < E_; k0 += 32) {
        const short8 af0 = *reinterpret_cast<const short8*>(
            A + (size_t)(m0 + col) * E_ + k0 + quad * 8);
        const short8 af1 = *reinterpret_cast<const short8*>(
            A + (size_t)(m0 + 16 + col) * E_ + k0 + quad * 8);
#pragma unroll
        for (int j = 0; j < 4; ++j) {
            const short8 bf = *reinterpret_cast<const short8*>(
                Wob + (size_t)(n0 + j * 16 + col) * E_ + k0 + quad * 8);
            acc[0][j] = __builtin_amdgcn_mfma_f32_16x16x32_bf16(af0, bf, acc[0][j], 0, 0, 0);
            acc[1][j] = __builtin_amdgcn_mfma_f32_16x16x32_bf16(af1, bf, acc[1][j], 0, 0, 0);
        }
    }
#pragma unroll
    for (int j = 0; j < 4; ++j) {
        const int n = n0 + j * 16 + col;
        const float bias = bo[n];
#pragma unroll
        for (int mi = 0; mi < 2; ++mi) {
#pragma unroll
            for (int r = 0; r < 4; ++r) {
                const int m = m0 + mi * 16 + quad * 4 + r;
                out[(size_t)m * E_ + n] = acc[mi][j][r] + bias;
            }
        }
    }
}

// ---------------------------------------------------------------------------
extern "C" void kernel_launch(void* const* d_in, const int* in_sizes, int n_in,
                              void* d_out, int out_size, void* d_ws, size_t ws_size,
                              hipStream_t stream)
{
    const float* emb = (const float*)d_in[0];
    const int*   msk = (const int*)d_in[1];
    const float* Wq  = (const float*)d_in[2];
    const float* Wk  = (const float*)d_in[3];
    const float* Wv  = (const float*)d_in[4];
    const float* Wo  = (const float*)d_in[5];
    const float* bo  = (const float*)d_in[6];
    float* out = (float*)d_out;

    const size_t nqkv = (size_t)B_ * H_ * S_ * DH_;        // 3,145,728 elems
    __hip_bfloat16* Q   = (__hip_bfloat16*)d_ws;
    __hip_bfloat16* Kp  = Q  + nqkv;
    __hip_bfloat16* Vt  = Kp + nqkv;
    __hip_bfloat16* att = Vt + nqkv;                        // [B][S][E] bf16
    unsigned int* mbits = (unsigned int*)((char*)d_ws + 4 * nqkv * sizeof(__hip_bfloat16));
    __hip_bfloat16* Wob = (__hip_bfloat16*)((char*)mbits + (size_t)B_ * S_ * SW_ * 4);
    // ws: 25.17 MB (Q/K/Vt/att) + 1 MB (mbits) + 1.18 MB (Wob) = 27.4 MB

    maskpack_kernel<<<(B_ * S_ * S_) / 256, 256, 0, stream>>>(msk, mbits);
    woconv_kernel  <<<(E_ * E_) / 1024,     256, 0, stream>>>(Wo, Wob);
    qkv_kernel <<<dim3(S_ / 64, B_ * H_), 256, 0, stream>>>(emb, Wq, Wk, Wv, Q, Kp, Vt);
    attn_kernel<<<dim3(S_ / 64, B_ * H_), 256, 0, stream>>>(Q, Kp, Vt, mbits, att);
    proj_kernel<<<dim3((B_ * S_) / 32, E_ / 256), 256, 0, stream>>>(att, Wob, bo, out);
}

// Round 4
// 314.080 us; speedup vs baseline: 1.1471x; 1.1471x over previous
//
#include <hip/hip_runtime.h>
#include <hip/hip_bf16.h>

#define B_  2
#define S_  2048
#define H_  24
#define DH_ 32
#define E_  768
#define SW_ (S_/32)   // mask words per row = 64

typedef __attribute__((ext_vector_type(8))) short short8;   // 8 x bf16 bits
typedef __attribute__((ext_vector_type(4))) float f32x4;

static __device__ __forceinline__ short bf16bits(float f) {
    __hip_bfloat16 h = __float2bfloat16(f);
    return *reinterpret_cast<short*>(&h);
}
static __device__ __forceinline__ float bf16tof(short s) {
    __hip_bfloat16 h = *reinterpret_cast<__hip_bfloat16*>(&s);
    return __bfloat162float(h);
}

// Q is pre-scaled by (1/sqrt(32)) * log2(e), so MFMA scores are already in
// the exp2 domain; the masked branch substitutes -1e-6*log2(e).
#define QSCALE  0.25503487f
#define MLOG2E -1.4426950e-6f

// ---------------------------------------------------------------------------
// Kernel 0a: pack int32 mask -> bitmask via wave ballot.
// ---------------------------------------------------------------------------
__global__ __launch_bounds__(256) void maskpack_kernel(
    const int* __restrict__ mask, unsigned int* __restrict__ mbits)
{
    const int idx  = blockIdx.x * 256 + threadIdx.x;
    const int lane = threadIdx.x & 63;
    const unsigned long long bal = __ballot(mask[idx] != 0);
    if (lane == 0) {
        uint2 w;
        w.x = (unsigned int)(bal & 0xffffffffull);
        w.y = (unsigned int)(bal >> 32);
        *reinterpret_cast<uint2*>(mbits + (idx >> 5)) = w;   // idx 64-aligned here
    }
}

// ---------------------------------------------------------------------------
// Kernel 0b: Wo fp32 -> bf16 (one-time)
// ---------------------------------------------------------------------------
__global__ __launch_bounds__(256) void woconv_kernel(
    const float* __restrict__ Wo, __hip_bfloat16* __restrict__ Wob)
{
    const int i = (blockIdx.x * 256 + threadIdx.x) * 4;
    const float4 w = *reinterpret_cast<const float4*>(Wo + i);
    short4 o;
    o.x = bf16bits(w.x); o.y = bf16bits(w.y);
    o.z = bf16bits(w.z); o.w = bf16bits(w.w);
    *reinterpret_cast<short4*>(Wob + i) = o;
}

// ---------------------------------------------------------------------------
// Kernel 1: per-head QKV projection, 64 s-rows/block.
// Q pre-scaled by QSCALE. V transposed through LDS -> coalesced 16B writes
// (the old direct store was 2B at 4KB stride = heavy write amplification).
// grid = (S/64, B*H), block = 256
// ---------------------------------------------------------------------------
__global__ __launch_bounds__(256) void qkv_kernel(
    const float* __restrict__ x,
    const float* __restrict__ Wq,
    const float* __restrict__ Wk,
    const float* __restrict__ Wv,
    __hip_bfloat16* __restrict__ Qo,
    __hip_bfloat16* __restrict__ Ko,
    __hip_bfloat16* __restrict__ Vto)
{
    const int bh = blockIdx.y;
    const int b  = bh / H_;
    const int h  = bh - b * H_;
    const int t  = threadIdx.x;
    const int e  = t & 31;
    const int sl = t >> 5;
    const int s0 = blockIdx.x * 64;

    __shared__ float xs[64][32];
    __shared__ float wqT[32][33];   // [e][d], +1 pad
    __shared__ float wkT[32][33];
    __shared__ float wvT[32][33];
    __shared__ __align__(16) __hip_bfloat16 vlds[32][72];  // [d][s], 16B-aligned rows

    const size_t wbase = (size_t)h * DH_ * DH_;
    for (int i = t; i < DH_ * DH_; i += 256) {
        const int d = i >> 5, ee = i & 31;
        wqT[ee][d] = Wq[wbase + i];
        wkT[ee][d] = Wk[wbase + i];
        wvT[ee][d] = Wv[wbase + i];
    }
#pragma unroll
    for (int rr = 0; rr < 8; ++rr) {
        const int sr = rr * 8 + sl;
        xs[sr][e] = x[((size_t)b * S_ + s0 + sr) * E_ + h * DH_ + e];
    }
    __syncthreads();

#pragma unroll
    for (int rr = 0; rr < 8; ++rr) {
        const int sr = rr * 8 + sl;
        const int s  = s0 + sr;
        float q = 0.f, k = 0.f, v = 0.f;
#pragma unroll
        for (int d = 0; d < DH_; ++d) {
            const float xv = xs[sr][d];
            q += xv * wqT[e][d];
            k += xv * wkT[e][d];
            v += xv * wvT[e][d];
        }
        const size_t rowq = ((size_t)bh * S_ + s) * DH_ + e;
        Qo[rowq] = __float2bfloat16(q * QSCALE);    // pre-scaled, exp2 domain
        Ko[rowq] = __float2bfloat16(k);
        vlds[e][sr] = __float2bfloat16(v);
    }
    __syncthreads();

    // coalesced Vt write: thread t -> row d=t>>3, 8 contiguous s at (t&7)*8
    const int d  = t >> 3;
    const int j0 = (t & 7) * 8;
    const short8 vrow = *reinterpret_cast<const short8*>(&vlds[d][j0]);
    *reinterpret_cast<short8*>(Vto + ((size_t)bh * DH_ + d) * S_ + s0 + j0) = vrow;
}

// ---------------------------------------------------------------------------
// Kernel 2: fused attention v3 (split-K).
//  - R2's lean 32-key loop (contiguous 1KB K/V frag loads).
//  - one broadcast mask word per q-row per 32 keys (bit-packed).
//  - scores already in exp2 domain (Q pre-scaled): per value cndmask + v_exp.
//  - double-buffered pbuf -> compiler can overlap iter i+1 loads/QK with
//    iter i softmax/PV.
//  - gridDim.z = parts (split along keys); O,l are additive (no running max
//    needed: |scores|<~1.5 by construction), partials written unnormalized.
// MFMA 16x16x32 bf16; C/D: col=lane&15, row=quad*4+reg (m89, HW-verified).
// grid = (S/64, B*H, parts), block = 256 (4 waves x 16 q-rows)
// ---------------------------------------------------------------------------
__global__ __launch_bounds__(256) void attn_kernel(
    const __hip_bfloat16* __restrict__ Q,     // [B*H][S][DH] (pre-scaled)
    const __hip_bfloat16* __restrict__ K,     // [B*H][S][DH]
    const __hip_bfloat16* __restrict__ Vt,    // [B*H][DH][S]
    const unsigned int* __restrict__ mbits,   // [B][S][S/32]
    __hip_bfloat16* __restrict__ Opart,       // [parts][B][S][E] unnormalized
    float* __restrict__ lpart)                // [parts][B*H][S]
{
    const int bh   = blockIdx.y;
    const int b    = bh / H_;
    const int h    = bh - b * H_;
    const int part = blockIdx.z;
    const int nkey = S_ / gridDim.z;
    const int kbeg = part * nkey;
    const int wave = threadIdx.x >> 6;
    const int lane = threadIdx.x & 63;
    const int col  = lane & 15;
    const int quad = lane >> 4;
    const int q0   = blockIdx.x * 64 + wave * 16;

    const __hip_bfloat16* Qbh = Q  + (size_t)bh * S_ * DH_;
    const __hip_bfloat16* Kbh = K  + (size_t)bh * S_ * DH_;
    const __hip_bfloat16* Vbh = Vt + (size_t)bh * DH_ * S_;
    const unsigned int*   mbb = mbits + (size_t)b * S_ * SW_;

    const short8 qfrag =
        *reinterpret_cast<const short8*>(Qbh + (size_t)(q0 + col) * DH_ + quad * 8);

    f32x4 o0 = {0.f,0.f,0.f,0.f};
    f32x4 o1 = {0.f,0.f,0.f,0.f};
    float lacc[4] = {0.f, 0.f, 0.f, 0.f};

    __shared__ __align__(16) __hip_bfloat16 pbuf[2][4][16][40];  // dbuf, 10.2KB

    for (int k0 = kbeg; k0 < kbeg + nkey; k0 += 32) {
        // independent loads first: mask words (broadcast within quad), K, V
        unsigned int mw[4];
#pragma unroll
        for (int r = 0; r < 4; ++r)
            mw[r] = mbb[(size_t)(q0 + quad * 4 + r) * SW_ + (k0 >> 5)];

        const short8 kf0 = *reinterpret_cast<const short8*>(
            Kbh + (size_t)(k0 + col) * DH_ + quad * 8);
        const short8 kf1 = *reinterpret_cast<const short8*>(
            Kbh + (size_t)(k0 + 16 + col) * DH_ + quad * 8);
        const short8 vf0 = *reinterpret_cast<const short8*>(
            Vbh + (size_t)col * S_ + k0 + quad * 8);
        const short8 vf1 = *reinterpret_cast<const short8*>(
            Vbh + (size_t)(16 + col) * S_ + k0 + quad * 8);

        const f32x4 z = {0.f, 0.f, 0.f, 0.f};
        f32x4 s0 = __builtin_amdgcn_mfma_f32_16x16x32_bf16(qfrag, kf0, z, 0, 0, 0);
        f32x4 s1 = __builtin_amdgcn_mfma_f32_16x16x32_bf16(qfrag, kf1, z, 0, 0, 0);

        __hip_bfloat16 (*pb)[40] = pbuf[(k0 >> 5) & 1][wave];
#pragma unroll
        for (int r = 0; r < 4; ++r) {
            // scores are log2-domain; masked -> -1e-6*log2e. One cndmask+exp2.
            const float t0 = ((mw[r] >> col)        & 1u) ? s0[r] : MLOG2E;
            const float t1 = ((mw[r] >> (col + 16)) & 1u) ? s1[r] : MLOG2E;
            const float p0 = exp2f(t0);
            const float p1 = exp2f(t1);
            lacc[r] += p0 + p1;
            pb[quad * 4 + r][col]      = __float2bfloat16(p0);
            pb[quad * 4 + r][16 + col] = __float2bfloat16(p1);
        }

        // C-layout -> A-layout via per-wave LDS round-trip (in-wave DS ordered)
        const short8 pfrag = *reinterpret_cast<const short8*>(&pb[col][quad * 8]);

        o0 = __builtin_amdgcn_mfma_f32_16x16x32_bf16(pfrag, vf0, o0, 0, 0, 0);
        o1 = __builtin_amdgcn_mfma_f32_16x16x32_bf16(pfrag, vf1, o1, 0, 0, 0);
    }

    __hip_bfloat16* obase = Opart + (size_t)part * B_ * S_ * E_;
#pragma unroll
    for (int r = 0; r < 4; ++r) {
        float l = lacc[r];
        l += __shfl_xor(l, 1);
        l += __shfl_xor(l, 2);
        l += __shfl_xor(l, 4);
        l += __shfl_xor(l, 8);
        const int qrow = q0 + quad * 4 + r;
        __hip_bfloat16* orow = obase + ((size_t)b * S_ + qrow) * E_ + h * DH_;
        orow[col]      = __float2bfloat16(o0[r]);   // unnormalized partial
        orow[16 + col] = __float2bfloat16(o1[r]);
        if (col == 0)
            lpart[((size_t)part * B_ * H_ + bh) * S_ + qrow] = l;
    }
}

// ---------------------------------------------------------------------------
// Kernel 2b: combine split-K partials: att = (sum_p O_p) / (sum_p l_p), bf16.
// Works in-place when Opart aliases att (parts==1 fallback).
// grid = B*S*E/1024, block=256, 4 elems/thread.
// ---------------------------------------------------------------------------
__global__ __launch_bounds__(256) void combine_kernel(
    const __hip_bfloat16* __restrict__ Opart,
    const float* __restrict__ lpart,
    __hip_bfloat16* __restrict__ att,
    int parts)
{
    const size_t idx4 = ((size_t)blockIdx.x * 256 + threadIdx.x) * 4;
    const int e  = (int)(idx4 % E_);
    const size_t bs = idx4 / E_;
    const int h  = e >> 5;
    const int b  = (int)(bs / S_);
    const int s  = (int)(bs % S_);

    float acc0 = 0.f, acc1 = 0.f, acc2 = 0.f, acc3 = 0.f, l = 0.f;
    for (int p = 0; p < parts; ++p) {
        const short4 ov = *reinterpret_cast<const short4*>(
            Opart + (size_t)p * B_ * S_ * E_ + idx4);
        acc0 += bf16tof(ov.x); acc1 += bf16tof(ov.y);
        acc2 += bf16tof(ov.z); acc3 += bf16tof(ov.w);
        l += lpart[((size_t)p * B_ * H_ + b * H_ + h) * S_ + s];
    }
    const float linv = 1.0f / l;
    short4 o;
    o.x = bf16bits(acc0 * linv); o.y = bf16bits(acc1 * linv);
    o.z = bf16bits(acc2 * linv); o.w = bf16bits(acc3 * linv);
    *reinterpret_cast<short4*>(att + idx4) = o;
}

// ---------------------------------------------------------------------------
// Kernel 3: output projection, bf16 Wo. Wave: 32 m x 64 n.
// grid = (M/32, 768/256), block = 256.
// ---------------------------------------------------------------------------
__global__ __launch_bounds__(256) void proj_kernel(
    const __hip_bfloat16* __restrict__ A,     // [4096][768] bf16 (ws)
    const __hip_bfloat16* __restrict__ Wob,   // [768][768] bf16 (ws)
    const float* __restrict__ bo,             // [768] fp32
    float* __restrict__ out)                  // [4096][768] fp32
{
    const int wave = threadIdx.x >> 6;
    const int lane = threadIdx.x & 63;
    const int col  = lane & 15;
    const int quad = lane >> 4;
    const int m0   = blockIdx.x * 32;
    const int n0   = blockIdx.y * 256 + wave * 64;

    f32x4 acc[2][4] = {{{0.f,0.f,0.f,0.f},{0.f,0.f,0.f,0.f},
                        {0.f,0.f,0.f,0.f},{0.f,0.f,0.f,0.f}},
                       {{0.f,0.f,0.f,0.f},{0.f,0.f,0.f,0.f},
                        {0.f,0.f,0.f,0.f},{0.f,0.f,0.f,0.f}}};
    for (int k0 = 0; k0 < E_; k0 += 32) {
        const short8 af0 = *reinterpret_cast<const short8*>(
            A + (size_t)(m0 + col) * E_ + k0 + quad * 8);
        const short8 af1 = *reinterpret_cast<const short8*>(
            A + (size_t)(m0 + 16 + col) * E_ + k0 + quad * 8);
#pragma unroll
        for (int j = 0; j < 4; ++j) {
            const short8 bf = *reinterpret_cast<const short8*>(
                Wob + (size_t)(n0 + j * 16 + col) * E_ + k0 + quad * 8);
            acc[0][j] = __builtin_amdgcn_mfma_f32_16x16x32_bf16(af0, bf, acc[0][j], 0, 0, 0);
            acc[1][j] = __builtin_amdgcn_mfma_f32_16x16x32_bf16(af1, bf, acc[1][j], 0, 0, 0);
        }
    }
#pragma unroll
    for (int j = 0; j < 4; ++j) {
        const int n = n0 + j * 16 + col;
        const float bias = bo[n];
#pragma unroll
        for (int mi = 0; mi < 2; ++mi) {
#pragma unroll
            for (int r = 0; r < 4; ++r) {
                const int m = m0 + mi * 16 + quad * 4 + r;
                out[(size_t)m * E_ + n] = acc[mi][j][r] + bias;
            }
        }
    }
}

// ---------------------------------------------------------------------------
extern "C" void kernel_launch(void* const* d_in, const int* in_sizes, int n_in,
                              void* d_out, int out_size, void* d_ws, size_t ws_size,
                              hipStream_t stream)
{
    const float* emb = (const float*)d_in[0];
    const int*   msk = (const int*)d_in[1];
    const float* Wq  = (const float*)d_in[2];
    const float* Wk  = (const float*)d_in[3];
    const float* Wv  = (const float*)d_in[4];
    const float* Wo  = (const float*)d_in[5];
    const float* bo  = (const float*)d_in[6];
    float* out = (float*)d_out;

    const size_t nqkv = (size_t)B_ * H_ * S_ * DH_;   // 3,145,728 (= B*S*E)
    char* p = (char*)d_ws;
    __hip_bfloat16* Q   = (__hip_bfloat16*)p;          p += nqkv * 2;
    __hip_bfloat16* Kp  = (__hip_bfloat16*)p;          p += nqkv * 2;
    __hip_bfloat16* Vt  = (__hip_bfloat16*)p;          p += nqkv * 2;
    __hip_bfloat16* att = (__hip_bfloat16*)p;          p += nqkv * 2;
    unsigned int*  mbits= (unsigned int*)p;            p += (size_t)B_ * S_ * SW_ * 4;
    __hip_bfloat16* Wob = (__hip_bfloat16*)p;          p += (size_t)E_ * E_ * 2;
    // split-K partials (after the 27.4MB base):
    __hip_bfloat16* Opart = (__hip_bfloat16*)p;
    float* lpart = (float*)(p + 2 * nqkv * 2);
    const size_t need2 = (size_t)(p - (char*)d_ws) + 2 * nqkv * 2
                       + (size_t)2 * B_ * H_ * S_ * 4;
    const size_t need1 = (size_t)(p - (char*)d_ws) + (size_t)B_ * H_ * S_ * 4;

    int parts;
    if (ws_size >= need2) {
        parts = 2;
    } else {
        parts = 1;
        Opart = att;                       // write unnormalized into att,
        lpart = (float*)p;                 // combine normalizes in-place
        (void)need1;
    }

    maskpack_kernel<<<(B_ * S_ * S_) / 256, 256, 0, stream>>>(msk, mbits);
    woconv_kernel  <<<(E_ * E_) / 1024,     256, 0, stream>>>(Wo, Wob);
    qkv_kernel <<<dim3(S_ / 64, B_ * H_), 256, 0, stream>>>(emb, Wq, Wk, Wv, Q, Kp, Vt);
    attn_kernel<<<dim3(S_ / 64, B_ * H_, parts), 256, 0, stream>>>(Q, Kp, Vt, mbits, Opart, lpart);
    combine_kernel<<<(B_ * S_ * E_) / 1024, 256, 0, stream>>>(Opart, lpart, att, parts);
    proj_kernel<<<dim3((B_ * S_) / 32, E_ / 256), 256, 0, stream>>>(att, Wob, bo, out);
}